// Round 4
// baseline (487.920 us; speedup 1.0000x reference)
//
#include <hip/hip_runtime.h>
#include <cstdint>
#include <cstddef>

// ---------------------------------------------------------------------------
// LSTM cell + 3-layer decoder, MI355X (gfx950)
// B=8192, H=1024, D_IN=1024, D1=512, D2=341(pad 384), A=512
// R4: (a) decoder rewritten barrier-free: B-fragments loaded directly
// global->VGPR (weights are L2-resident), A-tiles in LDS, zero syncthreads
// inside K-loops. (b) gates GEMM: XCD-aware block swizzle (each XCD owns a
// 4-wide tile_n slab -> its 2MB WALL slice stays L2-hot). (c) gates no
// longer writes H2 f16; decoder converts h f32->f16 during A staging.
// ---------------------------------------------------------------------------

typedef _Float16 half_t;
typedef _Float16 half8 __attribute__((ext_vector_type(8)));
typedef _Float16 half4v __attribute__((ext_vector_type(4)));
typedef float float4v __attribute__((ext_vector_type(4)));

#define GLD_LDS16(gptr, lptr)                                                  \
  __builtin_amdgcn_global_load_lds(                                            \
      (const __attribute__((address_space(1))) void*)(gptr),                   \
      (__attribute__((address_space(3))) void*)(lptr), 16, 0, 0)

__device__ __forceinline__ float fsig(float x) {
  return 1.0f / (1.0f + __expf(-x));
}
__device__ __forceinline__ float ftanh_(float x) {
  const float e = __expf(2.0f * x);
  return 1.0f - 2.0f / (e + 1.0f);
}

// ---------------------------------------------------------------------------
// Gates GEMM with fused LSTM epilogue, swizzled LDS staging, XCD-swizzled grid.
// A=XH [8192,2048], Bw=WALL [4096,2048], bias=BALL[4096], c [8192,1024].
// Column n: gate g=(n>>4)&3 == j-fragment index; unit u=((n>>6)<<4)|(n&15).
// Grid: 2048 1-D blocks; xcd=bid&7 owns tile_n in [xcd*4, xcd*4+4).
// ---------------------------------------------------------------------------
__global__ __launch_bounds__(256) void gemm_gates(const half_t* __restrict__ A,
                                                  const half_t* __restrict__ Bw,
                                                  const float* __restrict__ bias,
                                                  const float* __restrict__ cin,
                                                  float* __restrict__ hout) {
  constexpr int K = 2048;
  __shared__ alignas(16) half_t As[128 * 32];
  __shared__ alignas(16) half_t Bs[128 * 32];
  const int tid = threadIdx.x;
  const int lane = tid & 63;
  const int wave = tid >> 6;
  const int m = lane & 15;
  const int q = lane >> 4;
  const int sx = (m >> 1) & 3;  // fragment-read swizzle term

  // XCD-aware tile assignment: round-robin dispatch -> xcd = bid & 7
  const int bid = blockIdx.x;
  const int xcd = bid & 7;
  const int l = bid >> 3;  // 0..255 within XCD
  const size_t tile_n = (size_t)((xcd << 2) | (l & 3)) * 128;
  const size_t tile_m = (size_t)(l >> 2) * 128;
  const int wm = (wave >> 1) * 64;
  const int wn = (wave & 1) * 64;

  // swizzled staging: chunk c -> row=c>>2, kq=(c&3)^((row>>1)&3)
  const int cA0 = tid, rA0 = cA0 >> 2, kA0 = ((cA0 & 3) ^ ((rA0 >> 1) & 3));
  const int cA1 = 256 + tid, rA1 = cA1 >> 2, kA1 = ((cA1 & 3) ^ ((rA1 >> 1) & 3));
  const half_t* Ag0 = A + (tile_m + rA0) * (size_t)K + kA0 * 8;
  const half_t* Ag1 = A + (tile_m + rA1) * (size_t)K + kA1 * 8;
  const half_t* Bg0 = Bw + (tile_n + rA0) * (size_t)K + kA0 * 8;
  const half_t* Bg1 = Bw + (tile_n + rA1) * (size_t)K + kA1 * 8;
  const int p0 = cA0 * 16, p1 = cA1 * 16;

  float4v acc[4][4] = {};
  for (int k0 = 0; k0 < K; k0 += 32) {
    __syncthreads();
    GLD_LDS16(Ag0 + k0, (char*)As + p0);
    GLD_LDS16(Ag1 + k0, (char*)As + p1);
    GLD_LDS16(Bg0 + k0, (char*)Bs + p0);
    GLD_LDS16(Bg1 + k0, (char*)Bs + p1);
    __syncthreads();
    const int ks = (q ^ sx) * 8;
    half8 af[4], bf[4];
#pragma unroll
    for (int i = 0; i < 4; ++i)
      af[i] = *(const half8*)(As + (wm + i * 16 + m) * 32 + ks);
#pragma unroll
    for (int j = 0; j < 4; ++j)
      bf[j] = *(const half8*)(Bs + (wn + j * 16 + m) * 32 + ks);
#pragma unroll
    for (int i = 0; i < 4; ++i)
#pragma unroll
      for (int j = 0; j < 4; ++j)
        acc[i][j] =
            __builtin_amdgcn_mfma_f32_16x16x32_f16(af[i], bf[j], acc[i][j], 0, 0, 0);
  }

  // fused LSTM epilogue (C/D layout: col=lane&15, row=quad*4+reg [m89])
  const int nwave = (int)tile_n + wn;                // multiple of 64
  const size_t u = (size_t)((nwave >> 6) << 4) + m;  // hidden unit index
  float bg[4];
#pragma unroll
  for (int g = 0; g < 4; ++g) bg[g] = bias[nwave + g * 16 + m];
#pragma unroll
  for (int i = 0; i < 4; ++i) {
#pragma unroll
    for (int r = 0; r < 4; ++r) {
      const size_t row = tile_m + wm + q * 4 + i * 16 + r;
      const size_t off = row * 1024 + u;
      const float F = fsig(acc[i][0][r] + bg[0]);
      const float I = fsig(acc[i][1][r] + bg[1]);
      const float S = ftanh_(acc[i][2][r] + bg[2]);
      const float O = fsig(acc[i][3][r] + bg[3]);
      const float cn = cin[off] * F + I * S;
      const float hn = O * ftanh_(cn);
      hout[off] = hn;
    }
  }
}

// ---------------------------------------------------------------------------
// Fused decoder v2 -- barrier-free K-loops.
// 512 blocks x 256 threads (4 waves), 16 rows/block.
// A-tiles in LDS (As staged once from h f32, d1s/d2s produced in LDS);
// B-fragments loaded straight from global (weights are L2-resident, ~1.8 MB).
// Only 3 __syncthreads between layers + softmax reduction barriers.
// ---------------------------------------------------------------------------
__global__ __launch_bounds__(256) void decoder_fused(
    const float* __restrict__ hsrc,  // [8192,1024] f32 (= d_out from gates)
    const half_t* __restrict__ W1,   // [512,1024]
    const float* __restrict__ b1,    // [512]
    const half_t* __restrict__ W2,   // [384,512] (rows 341.. zero)
    const float* __restrict__ b2,    // [384] (341.. zero)
    const half_t* __restrict__ W3,   // [512,384] (cols 341.. zero)
    const float* __restrict__ b3,    // [512]
    float* __restrict__ out) {       // [8192,512]
  __shared__ alignas(16) half_t As[16 * 1032];   // 32.25 KB (pad 8)
  __shared__ alignas(16) half_t d1s[16 * 520];   // 16.25 KB (pad 8)
  __shared__ alignas(16) half_t d2s[16 * 392];   // 12.25 KB (pad 8)
  __shared__ float red[4 * 16];
  __shared__ float rowred[16];

  const int tid = threadIdx.x;
  const int lane = tid & 63;
  const int w = tid >> 6;  // 0..3
  const int m = lane & 15;
  const int q = lane >> 4;
  const size_t r0 = (size_t)blockIdx.x * 16;

  // ---- stage A: 16x1024 f32 -> f16 LDS (once) ----
#pragma unroll
  for (int i = 0; i < 16; ++i) {
    const int e = (tid + i * 256) * 4;  // 0..16380
    const int row = e >> 10, col = e & 1023;
    const float4v v = *(const float4v*)(hsrc + (r0 + row) * 1024 + col);
    half4v hv;
    hv.x = (half_t)v.x; hv.y = (half_t)v.y; hv.z = (half_t)v.z; hv.w = (half_t)v.w;
    *(half4v*)(As + row * 1032 + col) = hv;
  }
  __syncthreads();

  // ---- layer 1: 512 cols (128/wave, 8 j-tiles), K=1024, no barriers ----
  {
    float4v acc[8] = {};
    const int c0 = w * 128 + m;
    for (int kk = 0; kk < 1024; kk += 32) {
      const half8 af = *(const half8*)(As + m * 1032 + kk + q * 8);
      half8 bf[8];
#pragma unroll
      for (int j = 0; j < 8; ++j)
        bf[j] = *(const half8*)(W1 + (size_t)(c0 + j * 16) * 1024 + kk + q * 8);
#pragma unroll
      for (int j = 0; j < 8; ++j)
        acc[j] = __builtin_amdgcn_mfma_f32_16x16x32_f16(af, bf[j], acc[j], 0, 0, 0);
    }
#pragma unroll
    for (int j = 0; j < 8; ++j) {
      const int col = c0 + j * 16;
      const float bv = b1[col];
#pragma unroll
      for (int r = 0; r < 4; ++r)
        d1s[(q * 4 + r) * 520 + col] = (half_t)ftanh_(acc[j][r] + bv);
    }
  }
  __syncthreads();

  // ---- layer 2: 384 cols (96/wave, 6 j-tiles), K=512, no barriers ----
  {
    float4v acc[6] = {};
    const int c0 = w * 96 + m;
    for (int kk = 0; kk < 512; kk += 32) {
      const half8 af = *(const half8*)(d1s + m * 520 + kk + q * 8);
      half8 bf[6];
#pragma unroll
      for (int j = 0; j < 6; ++j)
        bf[j] = *(const half8*)(W2 + (size_t)(c0 + j * 16) * 512 + kk + q * 8);
#pragma unroll
      for (int j = 0; j < 6; ++j)
        acc[j] = __builtin_amdgcn_mfma_f32_16x16x32_f16(af, bf[j], acc[j], 0, 0, 0);
    }
#pragma unroll
    for (int j = 0; j < 6; ++j) {
      const int col = c0 + j * 16;
      const float bv = b2[col];
#pragma unroll
      for (int r = 0; r < 4; ++r)
        d2s[(q * 4 + r) * 392 + col] = (half_t)ftanh_(acc[j][r] + bv);
    }
  }
  __syncthreads();

  // ---- layer 3: 512 cols (128/wave, 8 j-tiles), K=384 + fused softmax ----
  {
    float4v acc[8] = {};
    const int c0 = w * 128 + m;
    for (int kk = 0; kk < 384; kk += 32) {
      const half8 af = *(const half8*)(d2s + m * 392 + kk + q * 8);
      half8 bf[8];
#pragma unroll
      for (int j = 0; j < 8; ++j)
        bf[j] = *(const half8*)(W3 + (size_t)(c0 + j * 16) * 384 + kk + q * 8);
#pragma unroll
      for (int j = 0; j < 8; ++j)
        acc[j] = __builtin_amdgcn_mfma_f32_16x16x32_f16(af, bf[j], acc[j], 0, 0, 0);
    }
    // logits: row = q*4+r, col = c0 + j*16
    float lg[8][4];
#pragma unroll
    for (int j = 0; j < 8; ++j) {
      const float bv = b3[c0 + j * 16];
#pragma unroll
      for (int r = 0; r < 4; ++r) lg[j][r] = acc[j][r] + bv;
    }
    // row max: in-lane over j, butterfly over m (stays within quad), LDS x-wave
    float pmax[4];
#pragma unroll
    for (int r = 0; r < 4; ++r) {
      float v = lg[0][r];
#pragma unroll
      for (int j = 1; j < 8; ++j) v = fmaxf(v, lg[j][r]);
#pragma unroll
      for (int d = 1; d < 16; d <<= 1) v = fmaxf(v, __shfl_xor(v, d, 64));
      pmax[r] = v;
    }
    if (m == 0) {
#pragma unroll
      for (int r = 0; r < 4; ++r) red[w * 16 + q * 4 + r] = pmax[r];
    }
    __syncthreads();
    if (tid < 16) {
      float v = red[tid];
#pragma unroll
      for (int ww = 1; ww < 4; ++ww) v = fmaxf(v, red[ww * 16 + tid]);
      rowred[tid] = v;
    }
    __syncthreads();
    float ex[8][4], psum[4];
#pragma unroll
    for (int r = 0; r < 4; ++r) {
      const float M = rowred[q * 4 + r];
      float s = 0.f;
#pragma unroll
      for (int j = 0; j < 8; ++j) {
        ex[j][r] = __expf(lg[j][r] - M);
        s += ex[j][r];
      }
#pragma unroll
      for (int d = 1; d < 16; d <<= 1) s += __shfl_xor(s, d, 64);
      psum[r] = s;
    }
    if (m == 0) {
#pragma unroll
      for (int r = 0; r < 4; ++r) red[w * 16 + q * 4 + r] = psum[r];
    }
    __syncthreads();
    if (tid < 16) {
      float s = 0.f;
#pragma unroll
      for (int ww = 0; ww < 4; ++ww) s += red[ww * 16 + tid];
      rowred[tid] = 1.0f / s;
    }
    __syncthreads();
#pragma unroll
    for (int r = 0; r < 4; ++r) {
      const int row = q * 4 + r;
      const float inv = rowred[row];
#pragma unroll
      for (int j = 0; j < 8; ++j)
        out[(r0 + row) * 512 + c0 + j * 16] = ex[j][r] * inv;
    }
  }
}

// ---------------------------------------------------------------------------
// prep_pack: blocks [0,16384) -> XH f16 [8192,2048]; [16384,24576) -> WALL.
// WALL row n: g=(n>>4)&3, u=((n>>6)<<4)|(n&15); cols 0..1023=W_gi[u], rest=W_gh[u]
// ---------------------------------------------------------------------------
__global__ void prep_pack(const float* __restrict__ x, const float* __restrict__ h,
                          const float* __restrict__ Wfi, const float* __restrict__ Wfh,
                          const float* __restrict__ Wii, const float* __restrict__ Wih,
                          const float* __restrict__ Wsi, const float* __restrict__ Wsh,
                          const float* __restrict__ Woi, const float* __restrict__ Woh,
                          half_t* __restrict__ xh, half_t* __restrict__ wall) {
  const int bid = blockIdx.x;
  const float* src;
  half_t* dst;
  size_t idx;
  if (bid < 16384) {
    idx = ((size_t)bid * 256 + threadIdx.x) * 4;
    const size_t b = idx >> 11;
    const int col = (int)(idx & 2047);
    src = (col < 1024) ? (x + b * 1024 + col) : (h + b * 1024 + (col - 1024));
    dst = xh + idx;
  } else {
    idx = ((size_t)(bid - 16384) * 256 + threadIdx.x) * 4;
    const int n = (int)(idx >> 11);
    const int col = (int)(idx & 2047);
    const int g = (n >> 4) & 3;
    const size_t u = (size_t)(((n >> 6) << 4) | (n & 15));
    const float* Wi = (g == 0) ? Wfi : (g == 1) ? Wii : (g == 2) ? Wsi : Woi;
    const float* Wh = (g == 0) ? Wfh : (g == 1) ? Wih : (g == 2) ? Wsh : Woh;
    src = (col < 1024) ? (Wi + u * 1024 + col) : (Wh + u * 1024 + (col - 1024));
    dst = wall + idx;
  }
  const float4v v = *(const float4v*)src;
  half4v o;
  o.x = (half_t)v.x; o.y = (half_t)v.y; o.z = (half_t)v.z; o.w = (half_t)v.w;
  *(half4v*)dst = o;
}

// ---------------------------------------------------------------------------
// prep_small: WD1 [0,512) | WD2 [512,704) | WD3 [704,896) | BALL [896,912) |
//             BD2 [912,914)
// ---------------------------------------------------------------------------
__global__ void prep_small(const float* __restrict__ Wd1, const float* __restrict__ Wd2,
                           const float* __restrict__ Wd3, const float* __restrict__ bd2,
                           const float* __restrict__ bfi, const float* __restrict__ bfh,
                           const float* __restrict__ bii, const float* __restrict__ bih,
                           const float* __restrict__ bsi, const float* __restrict__ bsh,
                           const float* __restrict__ boi, const float* __restrict__ boh,
                           half_t* __restrict__ WD1, half_t* __restrict__ WD2h,
                           half_t* __restrict__ WD3h, float* __restrict__ BALL,
                           float* __restrict__ BD2) {
  const int bid = blockIdx.x;
  const int tid = threadIdx.x;
  if (bid < 512) {  // WD1: [512,1024] f32 -> f16
    const size_t i4 = ((size_t)bid * 256 + tid) * 4;
    const float4v v = *(const float4v*)(Wd1 + i4);
    half4v o;
    o.x = (half_t)v.x; o.y = (half_t)v.y; o.z = (half_t)v.z; o.w = (half_t)v.w;
    *(half4v*)(WD1 + i4) = o;
  } else if (bid < 704) {  // WD2: [341,512] -> [384,512], row-padded
    const size_t i4 = ((size_t)(bid - 512) * 256 + tid) * 4;
    const int r = (int)(i4 >> 9);
    const int cc = (int)(i4 & 511);
    half4v o;
    if (r < 341) {
      const float4v v = *(const float4v*)(Wd2 + (size_t)r * 512 + cc);
      o.x = (half_t)v.x; o.y = (half_t)v.y; o.z = (half_t)v.z; o.w = (half_t)v.w;
    } else {
      o.x = (half_t)0.f; o.y = (half_t)0.f; o.z = (half_t)0.f; o.w = (half_t)0.f;
    }
    *(half4v*)(WD2h + i4) = o;
  } else if (bid < 896) {  // WD3: [512,341] -> [512,384], col-padded
    const size_t i4 = ((size_t)(bid - 704) * 256 + tid) * 4;
    const int r = (int)(i4 / 384);
    const int cc = (int)(i4 - (size_t)r * 384);
    half4v o;
    o.x = (cc + 0 < 341) ? (half_t)Wd3[(size_t)r * 341 + cc + 0] : (half_t)0.f;
    o.y = (cc + 1 < 341) ? (half_t)Wd3[(size_t)r * 341 + cc + 1] : (half_t)0.f;
    o.z = (cc + 2 < 341) ? (half_t)Wd3[(size_t)r * 341 + cc + 2] : (half_t)0.f;
    o.w = (cc + 3 < 341) ? (half_t)Wd3[(size_t)r * 341 + cc + 3] : (half_t)0.f;
    *(half4v*)(WD3h + i4) = o;
  } else if (bid < 912) {  // BALL[4096], WALL row ordering
    const int n = (bid - 896) * 256 + tid;
    const int g = (n >> 4) & 3;
    const int u = ((n >> 6) << 4) | (n & 15);
    const float* bi = (g == 0) ? bfi : (g == 1) ? bii : (g == 2) ? bsi : boi;
    const float* bh = (g == 0) ? bfh : (g == 1) ? bih : (g == 2) ? bsh : boh;
    BALL[n] = bi[u] + bh[u];
  } else {  // BD2[384]
    const int i = (bid - 912) * 256 + tid;
    if (i < 384) BD2[i] = (i < 341) ? bd2[i] : 0.0f;
  }
}

// ---------------------------------------------------------------------------
extern "C" void kernel_launch(void* const* d_in, const int* in_sizes, int n_in,
                              void* d_out, int out_size, void* d_ws, size_t ws_size,
                              hipStream_t stream) {
  const float* x = (const float*)d_in[0];
  const float* h = (const float*)d_in[1];
  const float* c = (const float*)d_in[2];
  const float* Wfi = (const float*)d_in[3];  const float* bfi = (const float*)d_in[4];
  const float* Wfh = (const float*)d_in[5];  const float* bfh = (const float*)d_in[6];
  const float* Wii = (const float*)d_in[7];  const float* bii = (const float*)d_in[8];
  const float* Wih = (const float*)d_in[9];  const float* bih = (const float*)d_in[10];
  const float* Wsi = (const float*)d_in[11]; const float* bsi = (const float*)d_in[12];
  const float* Wsh = (const float*)d_in[13]; const float* bsh = (const float*)d_in[14];
  const float* Woi = (const float*)d_in[15]; const float* boi = (const float*)d_in[16];
  const float* Woh = (const float*)d_in[17]; const float* boh = (const float*)d_in[18];
  const float* Wd1 = (const float*)d_in[19]; const float* bd1 = (const float*)d_in[20];
  const float* Wd2 = (const float*)d_in[21]; const float* bd2 = (const float*)d_in[22];
  const float* Wd3 = (const float*)d_in[23]; const float* bd3 = (const float*)d_in[24];

  char* ws = (char*)d_ws;
  size_t o = 0;
  auto alloc = [&](size_t bytes) {
    size_t cur = o;
    o += (bytes + 255) & ~(size_t)255;
    return cur;
  };
  half_t* XH   = (half_t*)(ws + alloc((size_t)8192 * 2048 * 2));  // 33.5 MB
  half_t* WALL = (half_t*)(ws + alloc((size_t)4096 * 2048 * 2));  // 16.8 MB
  float*  BALL = (float*)(ws + alloc(4096 * 4));
  half_t* WD1  = (half_t*)(ws + alloc((size_t)512 * 1024 * 2));
  half_t* WD2  = (half_t*)(ws + alloc((size_t)384 * 512 * 2));
  float*  BD2  = (float*)(ws + alloc(384 * 4));
  half_t* WD3  = (half_t*)(ws + alloc((size_t)512 * 384 * 2));

  float* h_out = (float*)d_out;                          // [8192,1024] f32
  float* d_outp = (float*)d_out + (size_t)8192 * 1024;   // [8192,512] f32

  // prep: 2 launches (inputs re-poisoned every call, so convert every call)
  prep_pack<<<24576, 256, 0, stream>>>(x, h, Wfi, Wfh, Wii, Wih, Wsi, Wsh, Woi, Woh,
                                       XH, WALL);
  prep_small<<<914, 256, 0, stream>>>(Wd1, Wd2, Wd3, bd2, bfi, bfh, bii, bih, bsi, bsh,
                                      boi, boh, WD1, WD2, WD3, BALL, BD2);

  // gates GEMM + fused LSTM -> h_out (f32); XCD-swizzled 1-D grid
  gemm_gates<<<2048, 256, 0, stream>>>(XH, WALL, BALL, c, h_out);

  // fused decoder (3 GEMMs + softmax, barrier-free K-loops)
  decoder_fused<<<512, 256, 0, stream>>>(h_out, WD1, bd1, WD2, BD2, WD3, bd3, d_outp);
}

// Round 5
// 441.203 us; speedup vs baseline: 1.1059x; 1.1059x over previous
//
#include <hip/hip_runtime.h>
#include <cstdint>
#include <cstddef>

// ---------------------------------------------------------------------------
// LSTM cell + 3-layer decoder, MI355X (gfx950)
// B=8192, H=1024, D_IN=1024, D1=512, D2=341(pad 384), A=512
// R5: persistent-weight barrier-free decoder. Each block stages a 32-column
// weight slab into padded LDS ONCE; activations move between layers in
// MFMA-A-fragment order (FRAG layout), so A-loads are single coalesced 1KB
// wave reads from global with NO barriers in any K-loop. Gates epilogue
// writes H2F in FRAG order (plus required h_out f32).
// FRAG(K) addr(row,k) = (row>>4)*16K + (k>>5)*512 + ((k>>3)&3)*128
//                       + (row&15)*8 + (k&7)   [halves]
// ---------------------------------------------------------------------------

typedef _Float16 half_t;
typedef _Float16 half8 __attribute__((ext_vector_type(8)));
typedef _Float16 half4v __attribute__((ext_vector_type(4)));
typedef float float4v __attribute__((ext_vector_type(4)));

#define GLD_LDS16(gptr, lptr)                                                  \
  __builtin_amdgcn_global_load_lds(                                            \
      (const __attribute__((address_space(1))) void*)(gptr),                   \
      (__attribute__((address_space(3))) void*)(lptr), 16, 0, 0)

__device__ __forceinline__ float fsig(float x) {
  return 1.0f / (1.0f + __expf(-x));
}
__device__ __forceinline__ float ftanh_(float x) {
  const float e = __expf(2.0f * x);
  return 1.0f - 2.0f / (e + 1.0f);
}

// ---------------------------------------------------------------------------
// Gates GEMM with fused LSTM epilogue, swizzled LDS staging, XCD-swizzled grid.
// Writes h_out (f32 row-major, output 0) and H2F (f16, FRAG(1024) order).
// ---------------------------------------------------------------------------
__global__ __launch_bounds__(256) void gemm_gates(const half_t* __restrict__ A,
                                                  const half_t* __restrict__ Bw,
                                                  const float* __restrict__ bias,
                                                  const float* __restrict__ cin,
                                                  float* __restrict__ hout,
                                                  half_t* __restrict__ h2f) {
  constexpr int K = 2048;
  __shared__ alignas(16) half_t As[128 * 32];
  __shared__ alignas(16) half_t Bs[128 * 32];
  const int tid = threadIdx.x;
  const int lane = tid & 63;
  const int wave = tid >> 6;
  const int m = lane & 15;
  const int q = lane >> 4;
  const int sx = (m >> 1) & 3;

  const int bid = blockIdx.x;
  const int xcd = bid & 7;
  const int l = bid >> 3;
  const size_t tile_n = (size_t)((xcd << 2) | (l & 3)) * 128;
  const size_t tile_m = (size_t)(l >> 2) * 128;
  const int wm = (wave >> 1) * 64;
  const int wn = (wave & 1) * 64;

  const int cA0 = tid, rA0 = cA0 >> 2, kA0 = ((cA0 & 3) ^ ((rA0 >> 1) & 3));
  const int cA1 = 256 + tid, rA1 = cA1 >> 2, kA1 = ((cA1 & 3) ^ ((rA1 >> 1) & 3));
  const half_t* Ag0 = A + (tile_m + rA0) * (size_t)K + kA0 * 8;
  const half_t* Ag1 = A + (tile_m + rA1) * (size_t)K + kA1 * 8;
  const half_t* Bg0 = Bw + (tile_n + rA0) * (size_t)K + kA0 * 8;
  const half_t* Bg1 = Bw + (tile_n + rA1) * (size_t)K + kA1 * 8;
  const int p0 = cA0 * 16, p1 = cA1 * 16;

  float4v acc[4][4] = {};
  for (int k0 = 0; k0 < K; k0 += 32) {
    __syncthreads();
    GLD_LDS16(Ag0 + k0, (char*)As + p0);
    GLD_LDS16(Ag1 + k0, (char*)As + p1);
    GLD_LDS16(Bg0 + k0, (char*)Bs + p0);
    GLD_LDS16(Bg1 + k0, (char*)Bs + p1);
    __syncthreads();
    const int ks = (q ^ sx) * 8;
    half8 af[4], bf[4];
#pragma unroll
    for (int i = 0; i < 4; ++i)
      af[i] = *(const half8*)(As + (wm + i * 16 + m) * 32 + ks);
#pragma unroll
    for (int j = 0; j < 4; ++j)
      bf[j] = *(const half8*)(Bs + (wn + j * 16 + m) * 32 + ks);
#pragma unroll
    for (int i = 0; i < 4; ++i)
#pragma unroll
      for (int j = 0; j < 4; ++j)
        acc[i][j] =
            __builtin_amdgcn_mfma_f32_16x16x32_f16(af[i], bf[j], acc[i][j], 0, 0, 0);
  }

  // fused LSTM epilogue (C/D: col=lane&15, row=q*4+reg [m89])
  const int nwave = (int)tile_n + wn;
  const int u = ((nwave >> 6) << 4) + m;  // hidden unit index
  const int rtb = (int)((tile_m + wm) >> 4);
  const int ubase = (u >> 5) * 512 + ((u >> 3) & 3) * 128 + (u & 7);
  float bg[4];
#pragma unroll
  for (int g = 0; g < 4; ++g) bg[g] = bias[nwave + g * 16 + m];
#pragma unroll
  for (int i = 0; i < 4; ++i) {
#pragma unroll
    for (int r = 0; r < 4; ++r) {
      const size_t row = tile_m + wm + q * 4 + i * 16 + r;
      const size_t off = row * 1024 + u;
      const float F = fsig(acc[i][0][r] + bg[0]);
      const float I = fsig(acc[i][1][r] + bg[1]);
      const float S = ftanh_(acc[i][2][r] + bg[2]);
      const float O = fsig(acc[i][3][r] + bg[3]);
      const float cn = cin[off] * F + I * S;
      const float hn = O * ftanh_(cn);
      hout[off] = hn;
      h2f[(size_t)(rtb + i) * 16384 + ubase + (q * 4 + r) * 8] = (half_t)hn;
    }
  }
}

// ---------------------------------------------------------------------------
// Decoder layer: out[col] over block's 32-col slab; A in FRAG(K) order.
// W slab staged to padded LDS once; NO barriers in the K-loop.
// MODE 0: out = f16 FRAG(OUTK) with tanh.  MODE 1: out = f32 row-major [*,512].
// Grid: (ncols/32, 64); 256 threads; wave handles 2 row-tiles (16 rows each).
// ---------------------------------------------------------------------------
template <int K, int OUTK, int MODE>
__global__ __launch_bounds__(256) void dec_layer(const half_t* __restrict__ Af,
                                                 const half_t* __restrict__ W,
                                                 const float* __restrict__ bias,
                                                 void* __restrict__ outp) {
  constexpr int KP = K + 8;           // pad: stride%128B==16B -> <=2-way banks
  constexpr int CH = K / 8;           // 16B chunks per slab column
  constexpr int ITER = 32 * CH / 256; // staging iterations
  __shared__ alignas(16) half_t Wl[32 * KP];
  const int tid = threadIdx.x;
  const int lane = tid & 63;
  const int w = tid >> 6;
  const int m = lane & 15;
  const int q = lane >> 4;
  const int g = blockIdx.x;

  // stage W slab (cols g*32 .. g*32+31), coalesced global -> padded LDS
#pragma unroll
  for (int it = 0; it < ITER; ++it) {
    const int ci = it * 256 + tid;
    const int c = ci / CH;
    const int kq = ci - c * CH;
    const half8 v = *(const half8*)(W + ((size_t)(g * 32 + c)) * K + kq * 8);
    *(half8*)(Wl + c * KP + kq * 8) = v;
  }
  __syncthreads();

  const int rt0 = blockIdx.y * 8 + w * 2;  // 2 row-tiles per wave
  const half_t* a0 = Af + (size_t)rt0 * (16 * K) + lane * 8;
  const half_t* a1 = a0 + 16 * K;
  float4v acc[2][2] = {};
#pragma unroll 2
  for (int kk = 0; kk < K; kk += 32) {
    const half8 af0 = *(const half8*)(a0 + kk * 16);  // 1KB coalesced wave read
    const half8 af1 = *(const half8*)(a1 + kk * 16);
    half8 bf[2];
#pragma unroll
    for (int j = 0; j < 2; ++j)
      bf[j] = *(const half8*)(Wl + (j * 16 + m) * KP + kk + q * 8);
    acc[0][0] = __builtin_amdgcn_mfma_f32_16x16x32_f16(af0, bf[0], acc[0][0], 0, 0, 0);
    acc[0][1] = __builtin_amdgcn_mfma_f32_16x16x32_f16(af0, bf[1], acc[0][1], 0, 0, 0);
    acc[1][0] = __builtin_amdgcn_mfma_f32_16x16x32_f16(af1, bf[0], acc[1][0], 0, 0, 0);
    acc[1][1] = __builtin_amdgcn_mfma_f32_16x16x32_f16(af1, bf[1], acc[1][1], 0, 0, 0);
  }

#pragma unroll
  for (int t = 0; t < 2; ++t) {
    const int rt = rt0 + t;
#pragma unroll
    for (int j = 0; j < 2; ++j) {
      const int col = g * 32 + j * 16 + m;
      const float bv = bias[col];
      if (MODE == 0) {
        half_t* of = (half_t*)outp;
        const size_t base = (size_t)rt * (16 * OUTK) + g * 512 +
                            (j * 2 + (m >> 3)) * 128 + (m & 7);
#pragma unroll
        for (int r = 0; r < 4; ++r)
          of[base + (q * 4 + r) * 8] = (half_t)ftanh_(acc[t][j][r] + bv);
      } else {
        float* ol = (float*)outp;
#pragma unroll
        for (int r = 0; r < 4; ++r)
          ol[((size_t)rt * 16 + q * 4 + r) * 512 + col] = acc[t][j][r] + bv;
      }
    }
  }
}

// ---------------------------------------------------------------------------
// softmax over rows of 512: one wave per row, 4 rows per block
// ---------------------------------------------------------------------------
__global__ __launch_bounds__(256) void softmax512(const float* __restrict__ logits,
                                                  float* __restrict__ out) {
  const int row = blockIdx.x * 4 + (threadIdx.x >> 6);
  const int lane = threadIdx.x & 63;
  const float4v* src = (const float4v*)(logits + (size_t)row * 512);
  const float4v v0 = src[lane * 2];
  const float4v v1 = src[lane * 2 + 1];
  float mx = fmaxf(fmaxf(fmaxf(v0.x, v0.y), fmaxf(v0.z, v0.w)),
                   fmaxf(fmaxf(v1.x, v1.y), fmaxf(v1.z, v1.w)));
#pragma unroll
  for (int off = 32; off > 0; off >>= 1) mx = fmaxf(mx, __shfl_xor(mx, off, 64));
  const float e0 = __expf(v0.x - mx), e1 = __expf(v0.y - mx);
  const float e2 = __expf(v0.z - mx), e3 = __expf(v0.w - mx);
  const float e4 = __expf(v1.x - mx), e5 = __expf(v1.y - mx);
  const float e6 = __expf(v1.z - mx), e7 = __expf(v1.w - mx);
  float sum = ((e0 + e1) + (e2 + e3)) + ((e4 + e5) + (e6 + e7));
#pragma unroll
  for (int off = 32; off > 0; off >>= 1) sum += __shfl_xor(sum, off, 64);
  const float inv = 1.0f / sum;
  float4v o0, o1;
  o0.x = e0 * inv; o0.y = e1 * inv; o0.z = e2 * inv; o0.w = e3 * inv;
  o1.x = e4 * inv; o1.y = e5 * inv; o1.z = e6 * inv; o1.w = e7 * inv;
  float4v* dst = (float4v*)(out + (size_t)row * 512);
  dst[lane * 2] = o0;
  dst[lane * 2 + 1] = o1;
}

// ---------------------------------------------------------------------------
// prep_pack: blocks [0,16384) -> XH f16 [8192,2048]; [16384,24576) -> WALL.
// ---------------------------------------------------------------------------
__global__ void prep_pack(const float* __restrict__ x, const float* __restrict__ h,
                          const float* __restrict__ Wfi, const float* __restrict__ Wfh,
                          const float* __restrict__ Wii, const float* __restrict__ Wih,
                          const float* __restrict__ Wsi, const float* __restrict__ Wsh,
                          const float* __restrict__ Woi, const float* __restrict__ Woh,
                          half_t* __restrict__ xh, half_t* __restrict__ wall) {
  const int bid = blockIdx.x;
  const float* src;
  half_t* dst;
  size_t idx;
  if (bid < 16384) {
    idx = ((size_t)bid * 256 + threadIdx.x) * 4;
    const size_t b = idx >> 11;
    const int col = (int)(idx & 2047);
    src = (col < 1024) ? (x + b * 1024 + col) : (h + b * 1024 + (col - 1024));
    dst = xh + idx;
  } else {
    idx = ((size_t)(bid - 16384) * 256 + threadIdx.x) * 4;
    const int n = (int)(idx >> 11);
    const int col = (int)(idx & 2047);
    const int g = (n >> 4) & 3;
    const size_t u = (size_t)(((n >> 6) << 4) | (n & 15));
    const float* Wi = (g == 0) ? Wfi : (g == 1) ? Wii : (g == 2) ? Wsi : Woi;
    const float* Wh = (g == 0) ? Wfh : (g == 1) ? Wih : (g == 2) ? Wsh : Woh;
    src = (col < 1024) ? (Wi + u * 1024 + col) : (Wh + u * 1024 + (col - 1024));
    dst = wall + idx;
  }
  const float4v v = *(const float4v*)src;
  half4v o;
  o.x = (half_t)v.x; o.y = (half_t)v.y; o.z = (half_t)v.z; o.w = (half_t)v.w;
  *(half4v*)dst = o;
}

// ---------------------------------------------------------------------------
// prep_small: WD1 [0,512) | WD2 [512,704) | WD3 [704,896) | BALL [896,912) |
//             BD2 [912,914)
// ---------------------------------------------------------------------------
__global__ void prep_small(const float* __restrict__ Wd1, const float* __restrict__ Wd2,
                           const float* __restrict__ Wd3, const float* __restrict__ bd2,
                           const float* __restrict__ bfi, const float* __restrict__ bfh,
                           const float* __restrict__ bii, const float* __restrict__ bih,
                           const float* __restrict__ bsi, const float* __restrict__ bsh,
                           const float* __restrict__ boi, const float* __restrict__ boh,
                           half_t* __restrict__ WD1, half_t* __restrict__ WD2h,
                           half_t* __restrict__ WD3h, float* __restrict__ BALL,
                           float* __restrict__ BD2) {
  const int bid = blockIdx.x;
  const int tid = threadIdx.x;
  if (bid < 512) {
    const size_t i4 = ((size_t)bid * 256 + tid) * 4;
    const float4v v = *(const float4v*)(Wd1 + i4);
    half4v o;
    o.x = (half_t)v.x; o.y = (half_t)v.y; o.z = (half_t)v.z; o.w = (half_t)v.w;
    *(half4v*)(WD1 + i4) = o;
  } else if (bid < 704) {
    const size_t i4 = ((size_t)(bid - 512) * 256 + tid) * 4;
    const int r = (int)(i4 >> 9);
    const int cc = (int)(i4 & 511);
    half4v o;
    if (r < 341) {
      const float4v v = *(const float4v*)(Wd2 + (size_t)r * 512 + cc);
      o.x = (half_t)v.x; o.y = (half_t)v.y; o.z = (half_t)v.z; o.w = (half_t)v.w;
    } else {
      o.x = (half_t)0.f; o.y = (half_t)0.f; o.z = (half_t)0.f; o.w = (half_t)0.f;
    }
    *(half4v*)(WD2h + i4) = o;
  } else if (bid < 896) {
    const size_t i4 = ((size_t)(bid - 704) * 256 + tid) * 4;
    const int r = (int)(i4 / 384);
    const int cc = (int)(i4 - (size_t)r * 384);
    half4v o;
    o.x = (cc + 0 < 341) ? (half_t)Wd3[(size_t)r * 341 + cc + 0] : (half_t)0.f;
    o.y = (cc + 1 < 341) ? (half_t)Wd3[(size_t)r * 341 + cc + 1] : (half_t)0.f;
    o.z = (cc + 2 < 341) ? (half_t)Wd3[(size_t)r * 341 + cc + 2] : (half_t)0.f;
    o.w = (cc + 3 < 341) ? (half_t)Wd3[(size_t)r * 341 + cc + 3] : (half_t)0.f;
    *(half4v*)(WD3h + i4) = o;
  } else if (bid < 912) {
    const int n = (bid - 896) * 256 + tid;
    const int g = (n >> 4) & 3;
    const int u = ((n >> 6) << 4) | (n & 15);
    const float* bi = (g == 0) ? bfi : (g == 1) ? bii : (g == 2) ? bsi : boi;
    const float* bh = (g == 0) ? bfh : (g == 1) ? bih : (g == 2) ? bsh : boh;
    BALL[n] = bi[u] + bh[u];
  } else {
    const int i = (bid - 912) * 256 + tid;
    if (i < 384) BD2[i] = (i < 341) ? bd2[i] : 0.0f;
  }
}

// ---------------------------------------------------------------------------
extern "C" void kernel_launch(void* const* d_in, const int* in_sizes, int n_in,
                              void* d_out, int out_size, void* d_ws, size_t ws_size,
                              hipStream_t stream) {
  const float* x = (const float*)d_in[0];
  const float* h = (const float*)d_in[1];
  const float* c = (const float*)d_in[2];
  const float* Wfi = (const float*)d_in[3];  const float* bfi = (const float*)d_in[4];
  const float* Wfh = (const float*)d_in[5];  const float* bfh = (const float*)d_in[6];
  const float* Wii = (const float*)d_in[7];  const float* bii = (const float*)d_in[8];
  const float* Wih = (const float*)d_in[9];  const float* bih = (const float*)d_in[10];
  const float* Wsi = (const float*)d_in[11]; const float* bsi = (const float*)d_in[12];
  const float* Wsh = (const float*)d_in[13]; const float* bsh = (const float*)d_in[14];
  const float* Woi = (const float*)d_in[15]; const float* boi = (const float*)d_in[16];
  const float* Woh = (const float*)d_in[17]; const float* boh = (const float*)d_in[18];
  const float* Wd1 = (const float*)d_in[19]; const float* bd1 = (const float*)d_in[20];
  const float* Wd2 = (const float*)d_in[21]; const float* bd2 = (const float*)d_in[22];
  const float* Wd3 = (const float*)d_in[23]; const float* bd3 = (const float*)d_in[24];

  char* ws = (char*)d_ws;
  size_t o = 0;
  auto alloc = [&](size_t bytes) {
    size_t cur = o;
    o += (bytes + 255) & ~(size_t)255;
    return cur;
  };
  half_t* XH   = (half_t*)(ws + alloc((size_t)8192 * 2048 * 2));  // 33.5 MB
  half_t* WALL = (half_t*)(ws + alloc((size_t)4096 * 2048 * 2));  // 16.8 MB
  float*  BALL = (float*)(ws + alloc(4096 * 4));
  half_t* WD1  = (half_t*)(ws + alloc((size_t)512 * 1024 * 2));
  half_t* WD2  = (half_t*)(ws + alloc((size_t)384 * 512 * 2));
  float*  BD2  = (float*)(ws + alloc(384 * 4));
  half_t* WD3  = (half_t*)(ws + alloc((size_t)512 * 384 * 2));
  half_t* H2F  = (half_t*)(ws + alloc((size_t)8192 * 1024 * 2));  // 16.8 MB frag
  half_t* D1F  = (half_t*)(ws + alloc((size_t)8192 * 512 * 2));   // 8.4 MB frag
  half_t* D2F  = (half_t*)(ws + alloc((size_t)8192 * 384 * 2));   // 6.3 MB frag
  float*  LOG  = (float*)XH;  // alias: XH dead after gates GEMM

  float* h_out = (float*)d_out;                          // [8192,1024] f32
  float* d_outp = (float*)d_out + (size_t)8192 * 1024;   // [8192,512] f32

  // prep: 2 launches (inputs re-poisoned every call, so convert every call)
  prep_pack<<<24576, 256, 0, stream>>>(x, h, Wfi, Wfh, Wii, Wih, Wsi, Wsh, Woi, Woh,
                                       XH, WALL);
  prep_small<<<914, 256, 0, stream>>>(Wd1, Wd2, Wd3, bd2, bfi, bfh, bii, bih, bsi, bsh,
                                      boi, boh, WD1, WD2, WD3, BALL, BD2);

  // gates GEMM + fused LSTM -> h_out (f32) + H2F (f16 frag order)
  gemm_gates<<<2048, 256, 0, stream>>>(XH, WALL, BALL, c, h_out, H2F);

  // decoder: persistent-weight barrier-free layers + softmax
  dec_layer<1024, 512, 0><<<dim3(16, 64), 256, 0, stream>>>(H2F, WD1, bd1, D1F);
  dec_layer<512, 384, 0><<<dim3(12, 64), 256, 0, stream>>>(D1F, WD2, BD2, D2F);
  dec_layer<384, 512, 1><<<dim3(16, 64), 256, 0, stream>>>(D2F, WD3, bd3, LOG);
  softmax512<<<2048, 256, 0, stream>>>(LOG, d_outp);
}